// Round 3
// baseline (375.486 us; speedup 1.0000x reference)
//
#include <hip/hip_runtime.h>

#define NSTATES 64

// Native clang vector types — required by __builtin_nontemporal_store
// (HIP's float4 is a class and is rejected).
typedef float f32x4 __attribute__((ext_vector_type(4)));
typedef float f32x2 __attribute__((ext_vector_type(2)));

// Viterbi ACS: one-hot gather + branch metric + pairwise max/argmax.
// 16 lanes per row, 4 states per lane. Per-lane edge constants hoisted out
// of the grid-stride row loop. All fp32 roundings are forced (weights are
// exactly {0,1}, llr signs exactly +-1) => bit-identical to numpy ref
// (verified: absmax 0.0 in R1).
//
// R2/R3: non-temporal stores for the 268 MB write stream (never re-read;
// keep it out of L2) + 2-row unroll for memory-level parallelism.
__global__ __launch_bounds__(256) void viterbi_acs_kernel(
    const float* __restrict__ in_prob,   // [B, 64]
    const float* __restrict__ llrs,      // [B, 2]
    const float* __restrict__ s2e,       // [64, 128]
    const float* __restrict__ mask,      // [64, 128]
    const float* __restrict__ l2e,       // [2, 128]
    float* __restrict__ out_max,         // [B, 64]
    float* __restrict__ out_ind,         // [B, 64] (0.0f / 1.0f)
    int batch)
{
    const int tid = blockIdx.x * blockDim.x + threadIdx.x;
    const int c = tid & 15;              // chunk within row: states 4c..4c+3

    // Per-chunk constants (independent of row): edge weights + llr sign rows.
    float w0[4], w1[4], t00[4], t01[4], t10[4], t11[4];
#pragma unroll
    for (int j = 0; j < 4; ++j) {
        const int d  = 4 * c + j;        // destination state
        const int e0 = 2 * d;            // competing edge 0
        const int e1 = 2 * d + 1;        // competing edge 1
        const int s0 = 2 * (d & 31);     // source state of edge 0
        const int s1 = s0 + 1;           // source state of edge 1
        w0[j]  = s2e[s0 * 128 + e0] * mask[s0 * 128 + e0];
        w1[j]  = s2e[s1 * 128 + e1] * mask[s1 * 128 + e1];
        t00[j] = l2e[e0];       t01[j] = l2e[128 + e0];
        t10[j] = l2e[e1];       t11[j] = l2e[128 + e1];
    }

    const int row0       = tid >> 4;
    const int row_stride = (int)((gridDim.x * blockDim.x) >> 4);
    const int coff       = (c & 7) * 8;  // input float offset for this lane

    int row = row0;
    // 2-row unrolled main loop.
    for (; row + row_stride < batch; row += 2 * row_stride) {
        const int rowB = row + row_stride;
        const float* rpA = in_prob + (size_t)row  * NSTATES + coff;
        const float* rpB = in_prob + (size_t)rowB * NSTATES + coff;

        // Issue all loads up front for MLP.
        const f32x4 vaA = *(const f32x4*)(rpA);
        const f32x4 vbA = *(const f32x4*)(rpA + 4);
        const f32x4 vaB = *(const f32x4*)(rpB);
        const f32x4 vbB = *(const f32x4*)(rpB + 4);
        const f32x2 lpA = *(const f32x2*)(llrs + (size_t)row  * 2);
        const f32x2 lpB = *(const f32x2*)(llrs + (size_t)rowB * 2);

        const float vA[8] = {vaA.x, vaA.y, vaA.z, vaA.w, vbA.x, vbA.y, vbA.z, vbA.w};
        const float vB[8] = {vaB.x, vaB.y, vaB.z, vaB.w, vbB.x, vbB.y, vbB.z, vbB.w};

        f32x4 mvA, ivA, mvB, ivB;
#pragma unroll
        for (int j = 0; j < 4; ++j) {
            const float bm0A = lpA.x * t00[j] + lpA.y * t01[j];
            const float bm1A = lpA.x * t10[j] + lpA.y * t11[j];
            const float x0A  = vA[2 * j]     * w0[j] + bm0A;
            const float x1A  = vA[2 * j + 1] * w1[j] + bm1A;
            mvA[j] = fmaxf(x0A, x1A);
            ivA[j] = (x1A > x0A) ? 1.0f : 0.0f;

            const float bm0B = lpB.x * t00[j] + lpB.y * t01[j];
            const float bm1B = lpB.x * t10[j] + lpB.y * t11[j];
            const float x0B  = vB[2 * j]     * w0[j] + bm0B;
            const float x1B  = vB[2 * j + 1] * w1[j] + bm1B;
            mvB[j] = fmaxf(x0B, x1B);
            ivB[j] = (x1B > x0B) ? 1.0f : 0.0f;
        }

        f32x4* omA = (f32x4*)(out_max + (size_t)row  * NSTATES + c * 4);
        f32x4* oiA = (f32x4*)(out_ind + (size_t)row  * NSTATES + c * 4);
        f32x4* omB = (f32x4*)(out_max + (size_t)rowB * NSTATES + c * 4);
        f32x4* oiB = (f32x4*)(out_ind + (size_t)rowB * NSTATES + c * 4);
        __builtin_nontemporal_store(mvA, omA);
        __builtin_nontemporal_store(ivA, oiA);
        __builtin_nontemporal_store(mvB, omB);
        __builtin_nontemporal_store(ivB, oiB);
    }
    // Tail (at most one row per thread).
    for (; row < batch; row += row_stride) {
        const float* rp = in_prob + (size_t)row * NSTATES + coff;
        const f32x4 va = *(const f32x4*)(rp);
        const f32x4 vb = *(const f32x4*)(rp + 4);
        const float v[8] = {va.x, va.y, va.z, va.w, vb.x, vb.y, vb.z, vb.w};
        const f32x2 lp = *(const f32x2*)(llrs + (size_t)row * 2);

        f32x4 mv, iv;
#pragma unroll
        for (int j = 0; j < 4; ++j) {
            const float bm0 = lp.x * t00[j] + lp.y * t01[j];
            const float bm1 = lp.x * t10[j] + lp.y * t11[j];
            const float x0  = v[2 * j]     * w0[j] + bm0;
            const float x1  = v[2 * j + 1] * w1[j] + bm1;
            mv[j] = fmaxf(x0, x1);
            iv[j] = (x1 > x0) ? 1.0f : 0.0f;
        }
        __builtin_nontemporal_store(mv, (f32x4*)(out_max + (size_t)row * NSTATES + c * 4));
        __builtin_nontemporal_store(iv, (f32x4*)(out_ind + (size_t)row * NSTATES + c * 4));
    }
}

extern "C" void kernel_launch(void* const* d_in, const int* in_sizes, int n_in,
                              void* d_out, int out_size, void* d_ws, size_t ws_size,
                              hipStream_t stream) {
    const float* in_prob = (const float*)d_in[0];
    const float* llrs    = (const float*)d_in[1];
    const float* s2e     = (const float*)d_in[2];
    const float* mask    = (const float*)d_in[3];
    const float* l2e     = (const float*)d_in[4];

    const int batch = in_sizes[0] / NSTATES;          // 524288
    float* out_max = (float*)d_out;                   // [B,64]
    float* out_ind = (float*)d_out + (size_t)batch * NSTATES;

    const int block = 256;
    const int grid  = 2048;   // 8 blocks/CU = 32 waves/CU; 16 rows/thread
    viterbi_acs_kernel<<<grid, block, 0, stream>>>(
        in_prob, llrs, s2e, mask, l2e, out_max, out_ind, batch);
}

// Round 4
// 371.579 us; speedup vs baseline: 1.0105x; 1.0105x over previous
//
#include <hip/hip_runtime.h>

#define NSTATES 64

// Native clang vector types — required by __builtin_nontemporal_{load,store}.
typedef float f32x4 __attribute__((ext_vector_type(4)));
typedef float f32x2 __attribute__((ext_vector_type(2)));

// Viterbi ACS: one-hot gather + branch metric + pairwise max/argmax.
//
// R4 mapping: 8 lanes per row, 8 destination states per lane (no duplicate
// loads — the old 16-lane mapping loaded every 32-B chunk twice per wave).
// Lane c loads sources 8c..8c+7 (two dwordx4, distinct & contiguous) and
// computes destinations {4c+j} and {32+4c+j}, j=0..3 — both halves consume
// the same source pair (8c+2j, 8c+2j+1), which is why the mapping closes.
// Arithmetic identical to R1 (absmax 0.0 proven): weights exactly {0,1},
// llr signs exactly +-1, all fp32 roundings forced => bit-exact vs numpy.
__global__ __launch_bounds__(256) void viterbi_acs_kernel(
    const float* __restrict__ in_prob,   // [B, 64]
    const float* __restrict__ llrs,      // [B, 2]
    const float* __restrict__ s2e,       // [64, 128]
    const float* __restrict__ mask,      // [64, 128]
    const float* __restrict__ l2e,       // [2, 128]
    float* __restrict__ out_max,         // [B, 64]
    float* __restrict__ out_ind,         // [B, 64] (0.0f / 1.0f)
    int batch)
{
    const int tid = blockIdx.x * blockDim.x + threadIdx.x;
    const int c = tid & 7;               // lane's source chunk: floats 8c..8c+7

    // Hoisted per-destination constants (row-invariant).
    // Low half: d = 4c+j. High half: d = 32+4c+j. Source s0 = 8c+2j for both.
    float wl0[4], wl1[4], tl00[4], tl01[4], tl10[4], tl11[4];
    float wh0[4], wh1[4], th00[4], th01[4], th10[4], th11[4];
#pragma unroll
    for (int j = 0; j < 4; ++j) {
        const int s0 = 8 * c + 2 * j;
        const int s1 = s0 + 1;
        {
            const int d  = 4 * c + j;
            const int e0 = 2 * d, e1 = 2 * d + 1;
            wl0[j]  = s2e[s0 * 128 + e0] * mask[s0 * 128 + e0];
            wl1[j]  = s2e[s1 * 128 + e1] * mask[s1 * 128 + e1];
            tl00[j] = l2e[e0];  tl01[j] = l2e[128 + e0];
            tl10[j] = l2e[e1];  tl11[j] = l2e[128 + e1];
        }
        {
            const int d  = 32 + 4 * c + j;
            const int e0 = 2 * d, e1 = 2 * d + 1;
            wh0[j]  = s2e[s0 * 128 + e0] * mask[s0 * 128 + e0];
            wh1[j]  = s2e[s1 * 128 + e1] * mask[s1 * 128 + e1];
            th00[j] = l2e[e0];  th01[j] = l2e[128 + e0];
            th10[j] = l2e[e1];  th11[j] = l2e[128 + e1];
        }
    }

    const int row0       = tid >> 3;
    const int row_stride = (int)((gridDim.x * blockDim.x) >> 3);

    for (int row = row0; row < batch; row += row_stride) {
        const float* rp = in_prob + (size_t)row * NSTATES + c * 8;
        const f32x4 va = __builtin_nontemporal_load((const f32x4*)rp);
        const f32x4 vb = __builtin_nontemporal_load((const f32x4*)(rp + 4));
        const f32x2 lp = __builtin_nontemporal_load((const f32x2*)(llrs + (size_t)row * 2));
        const float v[8] = {va.x, va.y, va.z, va.w, vb.x, vb.y, vb.z, vb.w};

        f32x4 mvl, ivl, mvh, ivh;
#pragma unroll
        for (int j = 0; j < 4; ++j) {
            const float p0 = v[2 * j];
            const float p1 = v[2 * j + 1];

            // low-half destination 4c+j
            const float bl0 = lp.x * tl00[j] + lp.y * tl01[j];
            const float bl1 = lp.x * tl10[j] + lp.y * tl11[j];
            const float xl0 = p0 * wl0[j] + bl0;
            const float xl1 = p1 * wl1[j] + bl1;
            mvl[j] = fmaxf(xl0, xl1);
            ivl[j] = (xl1 > xl0) ? 1.0f : 0.0f;   // first index wins ties

            // high-half destination 32+4c+j (same sources, different metrics)
            const float bh0 = lp.x * th00[j] + lp.y * th01[j];
            const float bh1 = lp.x * th10[j] + lp.y * th11[j];
            const float xh0 = p0 * wh0[j] + bh0;
            const float xh1 = p1 * wh1[j] + bh1;
            mvh[j] = fmaxf(xh0, xh1);
            ivh[j] = (xh1 > xh0) ? 1.0f : 0.0f;
        }

        float* om = out_max + (size_t)row * NSTATES;
        float* oi = out_ind + (size_t)row * NSTATES;
        __builtin_nontemporal_store(mvl, (f32x4*)(om + 4 * c));
        __builtin_nontemporal_store(mvh, (f32x4*)(om + 32 + 4 * c));
        __builtin_nontemporal_store(ivl, (f32x4*)(oi + 4 * c));
        __builtin_nontemporal_store(ivh, (f32x4*)(oi + 32 + 4 * c));
    }
}

extern "C" void kernel_launch(void* const* d_in, const int* in_sizes, int n_in,
                              void* d_out, int out_size, void* d_ws, size_t ws_size,
                              hipStream_t stream) {
    const float* in_prob = (const float*)d_in[0];
    const float* llrs    = (const float*)d_in[1];
    const float* s2e     = (const float*)d_in[2];
    const float* mask    = (const float*)d_in[3];
    const float* l2e     = (const float*)d_in[4];

    const int batch = in_sizes[0] / NSTATES;          // 524288
    float* out_max = (float*)d_out;                   // [B,64]
    float* out_ind = (float*)d_out + (size_t)batch * NSTATES;

    const int block = 256;
    const int grid  = 2048;   // 65536 row-slots; 8 rows per thread grid-stride
    viterbi_acs_kernel<<<grid, block, 0, stream>>>(
        in_prob, llrs, s2e, mask, l2e, out_max, out_ind, batch);
}